// Round 10
// baseline (901.300 us; speedup 1.0000x reference)
//
#include <hip/hip_runtime.h>
#include <hip/hip_fp16.h>
#include <type_traits>

// ---------------------------------------------------------------------------
// GCN 3-layer forward: N=50000, E=600000, dims 128 -> 128 -> 64 -> 16.
// r26 vs r25 (186.5; chunking reverted) / r23-r24 (172.6/175.7):
//  * aggmm REWRITTEN as edge-BALANCED aggregation into LDS f32 accumulators.
//    Mechanism: block gather time was max over 64 nodes' degrees (Poisson 12,
//    max~28) -> ~2x straggler inflation; matches the 2x gap between the
//    concurrency model (~23us) and measured (~44us), and explains the
//    r20/r23 occupancy nulls. Structure:
//      Acc[64][K+4] f32 in LDS. Round A: group g (8 lanes) = node g:
//      self-init row (plain stores, own-row only), process first <=8 edges
//      (one uint4 csr load = 8 slots), queue node if deg>8 (LDS queue).
//      Overflow: all 64 groups round-robin the (queued node, slot) grid ->
//      heavy tails spread across the whole block. Adds via atomicAdd
//      (ds_add_f32; <=2-way bank aliasing by construction). One barrier
//      chain; epilogue x di(dst) (dst factor folded out of edge weights,
//      r24 algebra), +bias, relu, repack fp16 IN PLACE (As aliases Acc);
//      MFMA phase unchanged. LDS 51.7KB -> 3 blocks/CU (24 waves, r19's
//      regime). Numerics: f32 add reorder only (~1e-6 << 2e-3 tol).
//  * gemm||scatter and agg_final byte-identical r24 (weight folding kept:
//    aggmm2 !PRE edge weight = rsqrt(cnt[src]+1) only; SCOUT prescales
//    outputs by dinv(row); aggmm3/final weightless).
// Dispatches: memset(cur) -> [gemm1||scatter] -> aggmm2 -> aggmm3 -> final.
// ---------------------------------------------------------------------------

typedef _Float16 f16x8 __attribute__((ext_vector_type(8)));
typedef float f32x4 __attribute__((ext_vector_type(4)));

#define CSR_CAP 32

__device__ inline float2 h2f(unsigned int u) {
  __half2 h = __builtin_bit_cast(__half2, u);
  return __half22float2(h);
}

// acc0/acc1 += fp16x8(g)   (weightless add for prescaled rows; agg_final)
__device__ inline void add8h(float4& a0, float4& a1, const uint4& g) {
  float2 f0 = h2f(g.x), f1 = h2f(g.y), f2 = h2f(g.z), f3 = h2f(g.w);
  a0.x += f0.x; a0.y += f0.y; a0.z += f1.x; a0.w += f1.y;
  a1.x += f2.x; a1.y += f2.y; a1.z += f3.x; a1.w += f3.y;
}

// LDS row += w * fp16x8(g) via ds f32 atomics (cross-group safe)
__device__ inline void acc8(float* row, const uint4& g, float w) {
  float2 f0 = h2f(g.x), f1 = h2f(g.y), f2 = h2f(g.z), f3 = h2f(g.w);
  atomicAdd(row + 0, f0.x * w);
  atomicAdd(row + 1, f0.y * w);
  atomicAdd(row + 2, f1.x * w);
  atomicAdd(row + 3, f1.y * w);
  atomicAdd(row + 4, f2.x * w);
  atomicAdd(row + 5, f2.y * w);
  atomicAdd(row + 6, f3.x * w);
  atomicAdd(row + 7, f3.y * w);
}

__device__ inline unsigned int pack2h(float x, float y) {
  __half2 h = __floats2half2_rn(x, y);
  return __builtin_bit_cast(unsigned int, h);
}

__device__ inline uint2 pack4h(const float4& v) {
  uint2 r;
  r.x = pack2h(v.x, v.y);
  r.y = pack2h(v.z, v.w);
  return r;
}

// -------------- GEMM (MFMA) with co-resident CSR scatter waves -------------
// Block = 512 threads. Threads [0,256): C16[n x F] = A[n x K] @ W[K x F];
//   W (f32) transposed+converted to fp16 LDS Ws[F][K+8]; 4 waves x 16 rows.
// Threads [256,512): grid-stride scatter, 4 edges/lane batches:
//   pos = atomic cursor on cur[d], store src id (ushort). cur[] ends the
//   dispatch equal to the in-degree histogram.
template <int K, int F, typename TIN>
__global__ __launch_bounds__(512) void gemm_mfma(const TIN* __restrict__ A,
                                                 const float* __restrict__ W,
                                                 __half* __restrict__ C16, int n,
                                                 int nwaves,
                                                 const int* __restrict__ src,
                                                 const int* __restrict__ dst,
                                                 int* __restrict__ cur,
                                                 unsigned short* __restrict__ csr,
                                                 int E) {
  constexpr int KP = K + 8;
  constexpr int KS = K / 32;
  constexpr int NT = F / 16;

  __shared__ __half Ws[F * KP];

  int t = threadIdx.x;

  if (t >= 256) {
    // ---- scatter waves (4-7) ----
    __syncthreads();  // rendezvous with gemm waves' post-staging barrier
    int base = blockIdx.x * 256 + (t - 256);
    int stride = gridDim.x * 256;
    for (int e0 = base; e0 < E; e0 += 4 * stride) {
      int d[4], s[4];
      bool v[4];
#pragma unroll
      for (int u = 0; u < 4; ++u) {
        int e = e0 + u * stride;
        v[u] = e < E;
        int ee = v[u] ? e : 0;
        d[u] = dst[ee];
        s[u] = src[ee];
      }
      int pos[4];
#pragma unroll
      for (int u = 0; u < 4; ++u)
        if (v[u]) pos[u] = atomicAdd(&cur[d[u]], 1);
#pragma unroll
      for (int u = 0; u < 4; ++u)
        if (v[u]) {
          int p = pos[u] >= CSR_CAP ? CSR_CAP - 1 : pos[u];  // mem safety
          csr[(size_t)d[u] * CSR_CAP + p] = (unsigned short)s[u];
        }
    }
    return;
  }

  // ---- gemm waves (0-3) ----
  for (int i = t; i < K * F; i += 256) {
    int kk = i / F, nn = i % F;
    Ws[nn * KP + kk] = __float2half(W[i]);
  }
  __syncthreads();  // only barrier

  int wave = blockIdx.x * 4 + (t >> 6);
  if (wave >= nwaves) return;
  int lane = t & 63;
  int m = lane & 15;
  int quad = lane >> 4;

  int arow = wave * 16 + m;
  if (arow >= n) arow = n - 1;  // clamp loads; stores guarded

  f16x8 af[KS];
  if constexpr (std::is_same_v<TIN, float>) {
#pragma unroll
    for (int ks = 0; ks < KS; ++ks) {
      const float* p = A + (size_t)arow * K + ks * 32 + quad * 8;
      float4 lo = *(const float4*)p;
      float4 hi = *(const float4*)(p + 4);
      f16x8 a;
      a[0] = (_Float16)lo.x; a[1] = (_Float16)lo.y;
      a[2] = (_Float16)lo.z; a[3] = (_Float16)lo.w;
      a[4] = (_Float16)hi.x; a[5] = (_Float16)hi.y;
      a[6] = (_Float16)hi.z; a[7] = (_Float16)hi.w;
      af[ks] = a;
    }
  } else {
#pragma unroll
    for (int ks = 0; ks < KS; ++ks)
      af[ks] = *(const f16x8*)(const void*)&A[(size_t)arow * K + ks * 32 + quad * 8];
  }

  f32x4 acc[NT];
#pragma unroll
  for (int nt = 0; nt < NT; ++nt) acc[nt] = (f32x4){0.f, 0.f, 0.f, 0.f};
#pragma unroll
  for (int nt = 0; nt < NT; ++nt)
#pragma unroll
    for (int ks = 0; ks < KS; ++ks) {
      f16x8 b = *(const f16x8*)(const void*)&Ws[(nt * 16 + m) * KP + ks * 32 + quad * 8];
      acc[nt] = __builtin_amdgcn_mfma_f32_16x16x32_f16(af[ks], b, acc[nt], 0, 0, 0);
    }

  int rbase = wave * 16 + quad * 4;
#pragma unroll
  for (int nt = 0; nt < NT; ++nt)
#pragma unroll
    for (int r = 0; r < 4; ++r) {
      int rr = rbase + r;
      if (rr < n) C16[(size_t)rr * F + nt * 16 + m] = __float2half(acc[nt][r]);
    }
}

// ------------- Balanced aggregate + GEMM (LDS f32 Acc, MFMA) ---------------
// C16[n x F] = [relu(di*Agg(hprev) + bias) @ W] (* dinv(row) if SCOUT).
// Block = 512 thr = 64 nodes; group g = 8 lanes owns node g.
// Round A: self-init + first <=8 edges per node; deg>8 nodes -> LDS queue.
// Overflow: 64 groups round-robin the (queued node, slot) grid (balanced).
// Adds: atomicAdd f32 into Acc[64][K+4]. Epilogue: x di, +bias, relu,
// repack fp16 in place (As aliases Acc). MFMA: waves 0-3, one tile each.
// PRE: hprev rows prescaled by dinv[src] -> weightless edge adds.
// !PRE: edge weight = rsqrt(cnt[src]+1) only (dst factor in epilogue di).
template <int K, int F, bool PRE, bool SCOUT>
__global__ __launch_bounds__(512) void aggmm_bal(
    const __half* __restrict__ hprev, const float* __restrict__ W,
    const float* __restrict__ bias, const int* __restrict__ cnt,
    const unsigned short* __restrict__ csr, __half* __restrict__ C16, int n) {
  constexpr int KP = K + 8;   // fp16 As row stride
  constexpr int KA = K + 4;   // f32 Acc row stride
  constexpr int KS = K / 32;
  constexpr int NT = F / 16;
  constexpr int RS = K / 8;   // uint4 per hprev row
  constexpr int CPL = K / 64; // uint4 loads per lane per row

  __shared__ __half Ws[F * KP];
  __shared__ float Acc[64 * KA];
  __shared__ int qn[64];
  __shared__ int qtot;
  __shared__ int mcc;
  __shared__ int ccs[64];

  int t = threadIdx.x;
  if (t == 0) { qtot = 0; mcc = 8; }
  for (int i = t; i < K * F; i += 512) {
    int kk = i / F, nn = i % F;
    Ws[nn * KP + kk] = __float2half(W[i]);
  }
  __syncthreads();  // (1) queue init visible

  int g = t >> 3;  // node-in-block (0..63)
  int fl = t & 7;  // chunk lane
  int nb = blockIdx.x * 64;
  int node = nb + g;
  int nd = node < n ? node : n - 1;  // clamp (dup rows discarded at store)
  const uint4* h4 = (const uint4*)hprev;

  // ---- round A: self-init + first <=8 edges of own node ----
  {
    int c0 = cnt[nd];
    float di = rsqrtf((float)c0 + 1.0f);
    int cc = c0 < CSR_CAP ? c0 : CSR_CAP;
    float sf = PRE ? 1.0f : di;  // self: (PRE: di applied at epilogue) else di^2 total
#pragma unroll
    for (int c = 0; c < CPL; ++c) {
      uint4 sv = h4[(size_t)nd * RS + c * 8 + fl];
      float2 f0 = h2f(sv.x), f1 = h2f(sv.y), f2 = h2f(sv.z), f3 = h2f(sv.w);
      float* row = &Acc[g * KA + c * 64 + fl * 8];
      row[0] = f0.x * sf; row[1] = f0.y * sf; row[2] = f1.x * sf; row[3] = f1.y * sf;
      row[4] = f2.x * sf; row[5] = f2.y * sf; row[6] = f3.x * sf; row[7] = f3.y * sf;
    }
    if (fl == 0) {
      ccs[g] = cc;
      if (cc > 8) {
        qn[atomicAdd(&qtot, 1)] = g;
        atomicMax(&mcc, cc);
      }
    }
    int m8 = cc < 8 ? cc : 8;
    if (m8 > 0) {
      uint4 pk = *(const uint4*)&csr[(size_t)nd * CSR_CAP];  // slots 0..7
      int s[8] = {(int)(pk.x & 0xffff), (int)(pk.x >> 16),
                  (int)(pk.y & 0xffff), (int)(pk.y >> 16),
                  (int)(pk.z & 0xffff), (int)(pk.z >> 16),
                  (int)(pk.w & 0xffff), (int)(pk.w >> 16)};
      float* arow = &Acc[g * KA];
#pragma unroll
      for (int u = 0; u < 8; u += 2) {
        if (u >= m8) break;
        int p0 = s[u];
        bool v1 = (u + 1) < m8;
        int p1 = v1 ? s[u + 1] : p0;  // guarded dup (never OOB)
        uint4 g0[CPL], g1[CPL];
#pragma unroll
        for (int c = 0; c < CPL; ++c) {
          g0[c] = h4[(size_t)p0 * RS + c * 8 + fl];
          g1[c] = h4[(size_t)p1 * RS + c * 8 + fl];
        }
        float w0 = 1.0f, w1 = 1.0f;
        if constexpr (!PRE) {
          w0 = rsqrtf((float)cnt[p0] + 1.0f);
          w1 = rsqrtf((float)cnt[p1] + 1.0f);
        }
#pragma unroll
        for (int c = 0; c < CPL; ++c) acc8(arow + c * 64 + fl * 8, g0[c], w0);
        if (v1) {
#pragma unroll
          for (int c = 0; c < CPL; ++c) acc8(arow + c * 64 + fl * 8, g1[c], w1);
        }
      }
    }
  }

  __syncthreads();  // (2) queue complete

  // ---- overflow: balanced round-robin over (queued node, slot>=8) ----
  {
    int qt = qtot;
    int rmax = mcc - 8;  // <= CSR_CAP-8
    if (qt > 0 && rmax > 0) {
      int total = qt * rmax;
      int qi = g, r = 0;
      while (qi >= qt) { qi -= qt; ++r; }
      for (int k = g; k < total; k += 64) {
        int nib2 = qn[qi];
        int slot = 8 + r;
        if (slot < ccs[nib2]) {
          int nd2 = nb + nib2;
          if (nd2 >= n) nd2 = n - 1;
          int p = csr[(size_t)nd2 * CSR_CAP + slot];
          uint4 gg[CPL];
#pragma unroll
          for (int c = 0; c < CPL; ++c) gg[c] = h4[(size_t)p * RS + c * 8 + fl];
          float w = 1.0f;
          if constexpr (!PRE) w = rsqrtf((float)cnt[p] + 1.0f);
          float* arow = &Acc[nib2 * KA];
#pragma unroll
          for (int c = 0; c < CPL; ++c) acc8(arow + c * 64 + fl * 8, gg[c], w);
        }
        qi += 64;
        while (qi >= qt) { qi -= qt; ++r; }
      }
    }
  }

  __syncthreads();  // (3) all adds complete

  // ---- epilogue: x di, +bias, relu -> regs ----
  float di2 = rsqrtf((float)cnt[nd] + 1.0f);
  float4 rv[CPL][2];
#pragma unroll
  for (int c = 0; c < CPL; ++c) {
    const float* row = &Acc[g * KA + c * 64 + fl * 8];
    float4 a = *(const float4*)row;
    float4 b = *(const float4*)(row + 4);
    int col = c * 64 + fl * 8;
    float4 b0 = *(const float4*)&bias[col];
    float4 b1 = *(const float4*)&bias[col + 4];
    rv[c][0] = make_float4(fmaxf(a.x * di2 + b0.x, 0.f), fmaxf(a.y * di2 + b0.y, 0.f),
                           fmaxf(a.z * di2 + b0.z, 0.f), fmaxf(a.w * di2 + b0.w, 0.f));
    rv[c][1] = make_float4(fmaxf(b.x * di2 + b1.x, 0.f), fmaxf(b.y * di2 + b1.y, 0.f),
                           fmaxf(b.z * di2 + b1.z, 0.f), fmaxf(b.w * di2 + b1.w, 0.f));
  }

  __syncthreads();  // (4) reads done before fp16 repack aliases Acc

  __half* As = (__half*)Acc;  // [64][KP] fp16, fits in Acc region
#pragma unroll
  for (int c = 0; c < CPL; ++c) {
    int col = c * 64 + fl * 8;
    uint2 lo = pack4h(rv[c][0]), hi = pack4h(rv[c][1]);
    uint4 pk2;
    pk2.x = lo.x; pk2.y = lo.y; pk2.z = hi.x; pk2.w = hi.y;
    *(uint4*)&As[(size_t)g * KP + col] = pk2;
  }

  __syncthreads();  // (5) As ready

  // ---- MFMA phase (waves 0-3, one 16-row tile each) ----
  int wid = t >> 6;
  int lane = t & 63;
  if (wid < 4) {
    int m = lane & 15;
    int quad = lane >> 4;
    const __half* At = &As[(size_t)wid * 16 * KP];
    f16x8 af[KS];
#pragma unroll
    for (int ks = 0; ks < KS; ++ks)
      af[ks] = *(const f16x8*)(const void*)&At[m * KP + ks * 32 + quad * 8];

    f32x4 acc2[NT];
#pragma unroll
    for (int nt = 0; nt < NT; ++nt) acc2[nt] = (f32x4){0.f, 0.f, 0.f, 0.f};
#pragma unroll
    for (int nt = 0; nt < NT; ++nt)
#pragma unroll
      for (int ks = 0; ks < KS; ++ks) {
        f16x8 bfr = *(const f16x8*)(const void*)&Ws[(nt * 16 + m) * KP + ks * 32 + quad * 8];
        acc2[nt] = __builtin_amdgcn_mfma_f32_16x16x32_f16(af[ks], bfr, acc2[nt], 0, 0, 0);
      }

    int rbase = nb + wid * 16 + quad * 4;
    float rw[4];
#pragma unroll
    for (int r = 0; r < 4; ++r) {
      if constexpr (SCOUT) {
        int rr = rbase + r;
        int rc = rr < n ? rr : n - 1;
        rw[r] = rsqrtf((float)cnt[rc] + 1.0f);
      } else {
        rw[r] = 1.0f;
      }
    }
#pragma unroll
    for (int nt = 0; nt < NT; ++nt)
#pragma unroll
      for (int r = 0; r < 4; ++r) {
        int rr = rbase + r;
        if (rr < n) C16[(size_t)rr * F + nt * 16 + m] = __float2half(acc2[nt][r] * rw[r]);
      }
  }
}

// ------------------------------ Final aggregation --------------------------
// out[i] = di * (sum t3'[p] + t3'[i]) + bias  (t3' prescaled by dinv[row];
// f32 out, F=16). 4 lanes/node: 2 edge-halves x 2 chunk-lanes; halves
// combined via shfl_xor(2). 64 nodes/block. No per-edge weight loads.
__global__ __launch_bounds__(256) void agg_final(
    const __half* __restrict__ h16, const int* __restrict__ cnt,
    const unsigned short* __restrict__ csr, const float* __restrict__ bias,
    float* __restrict__ out, int n) {
  int node = blockIdx.x * 64 + threadIdx.x / 4;
  int q = threadIdx.x & 3;
  int half = q >> 1;
  int fl = q & 1;
  bool valid = node < n;
  int nd = valid ? node : n - 1;

  const uint4* h4 = (const uint4*)h16;  // 2 uint4 per row
  int c0 = cnt[nd];
  float di = rsqrtf((float)c0 + 1.0f);
  int cc = c0 < CSR_CAP ? c0 : CSR_CAP;
  float4 a0 = make_float4(0.f, 0.f, 0.f, 0.f);
  float4 a1 = make_float4(0.f, 0.f, 0.f, 0.f);
  if (half == 0) {
    uint4 sv = h4[(size_t)nd * 2 + fl];
    add8h(a0, a1, sv);  // prescaled self row; di applied at the end
  }
  int s = nd * CSR_CAP;
  int e = s + cc;
  int j = s + half;
  for (; j + 2 < e; j += 4) {  // edges j, j+2 (this half's stride-2 stream)
    int p0 = csr[j];
    int p1 = csr[j + 2];
    uint4 g0 = h4[(size_t)p0 * 2 + fl];
    uint4 g1 = h4[(size_t)p1 * 2 + fl];
    add8h(a0, a1, g0);
    add8h(a0, a1, g1);
  }
  for (; j < e; j += 2) {
    int p = csr[j];
    uint4 g = h4[(size_t)p * 2 + fl];
    add8h(a0, a1, g);
  }

  // combine the two edge-halves (xor lane by 2 keeps fl, flips half)
  a0.x += __shfl_xor(a0.x, 2);
  a0.y += __shfl_xor(a0.y, 2);
  a0.z += __shfl_xor(a0.z, 2);
  a0.w += __shfl_xor(a0.w, 2);
  a1.x += __shfl_xor(a1.x, 2);
  a1.y += __shfl_xor(a1.y, 2);
  a1.z += __shfl_xor(a1.z, 2);
  a1.w += __shfl_xor(a1.w, 2);

  if (valid && half == 0) {
    float4 b0 = *(const float4*)&bias[fl * 8];
    float4 b1 = *(const float4*)&bias[fl * 8 + 4];
    float4 r0 = make_float4(a0.x * di + b0.x, a0.y * di + b0.y,
                            a0.z * di + b0.z, a0.w * di + b0.w);
    float4 r1 = make_float4(a1.x * di + b1.x, a1.y * di + b1.y,
                            a1.z * di + b1.z, a1.w * di + b1.w);
    float* op = &out[(size_t)node * 16 + fl * 8];
    *(float4*)op = r0;
    *(float4*)(op + 4) = r1;
  }
}

// -------------------------------- launch -----------------------------------

extern "C" void kernel_launch(void* const* d_in, const int* in_sizes, int n_in,
                              void* d_out, int out_size, void* d_ws, size_t ws_size,
                              hipStream_t stream) {
  const float* x = (const float*)d_in[0];
  const int* edge = (const int*)d_in[1];
  const float* W1 = (const float*)d_in[2];
  const float* b1 = (const float*)d_in[3];
  const float* W2 = (const float*)d_in[4];
  const float* b2 = (const float*)d_in[5];
  const float* W3 = (const float*)d_in[6];
  const float* b3 = (const float*)d_in[7];

  const int N = in_sizes[0] / 128;
  const int E = in_sizes[1] / 2;
  const int* src = edge;       // edge_index[0]
  const int* dstp = edge + E;  // edge_index[1]
  float* out = (float*)d_out;

  size_t off = 0;
  auto take = [&](size_t bytes) -> void* {
    void* r = (char*)d_ws + off;
    off += (bytes + 255) & ~(size_t)255;
    return r;
  };
  int* cur = (int*)take((size_t)N * 4);  // cursors -> in-degrees
  unsigned short* csr =
      (unsigned short*)take((size_t)N * CSR_CAP * 2 + 256);  // ushort CSR + pad
  __half* t1 = (__half*)take((size_t)N * 128 * 2);           // gemm1 out (unscaled)
  __half* t2 = (__half*)take((size_t)N * 64 * 2);            // aggmm2 out (prescaled)
  __half* t3 = (__half*)take((size_t)N * 16 * 2);            // aggmm3 out (prescaled)

  // zero cur (first region only)
  hipMemsetAsync(d_ws, 0, ((size_t)N * 4 + 255) & ~(size_t)255, stream);

  int nwaves = (N + 15) / 16;   // 3125
  int gblk = (nwaves + 3) / 4;  // 782
  int fblk = (N + 63) / 64;     // 782 (64 nodes/block)

  // gemm1 with co-resident CSR scatter (waves 4-7 of every block grid-stride
  // the edge list; cur[] ends this dispatch holding the in-degree histogram).
  gemm_mfma<128, 128, float><<<gblk, 512, 0, stream>>>(x, W1, t1, N, nwaves,
                                                       src, dstp, cur, csr, E);

  // t2' = [relu(di*Agg_w(t1)+b1) @ W2] * dinv(row)  (balanced; w=rsqrt(cnt_s+1))
  aggmm_bal<128, 64, false, true><<<fblk, 512, 0, stream>>>(t1, W2, b1, cur, csr, t2, N);
  // t3' = [relu(di*Sum(t2')+b2) @ W3] * dinv(row)   (balanced; weightless)
  aggmm_bal<64, 16, true, true><<<fblk, 512, 0, stream>>>(t2, W3, b2, cur, csr, t3, N);
  // out = di*Sum(t3') + b3                          (weightless adds)
  agg_final<<<fblk, 256, 0, stream>>>(t3, cur, csr, b3, out, N);
}

// Round 11
// 171.300 us; speedup vs baseline: 5.2615x; 5.2615x over previous
//
#include <hip/hip_runtime.h>
#include <hip/hip_fp16.h>
#include <type_traits>

// ---------------------------------------------------------------------------
// GCN 3-layer forward: N=50000, E=600000, dims 128 -> 128 -> 64 -> 16.
// r27 == r19 RESTORED (best measured: 172.0 us). Post-r19 experiment ledger:
//   r20 gather-data pipeline      -> +4.4 us (VGPR cost > latency gain)
//   r21 ushort/CAP32 CSR          -> neutral (atomic RMW stream invariant)
//   r22 persistent fused tail     -> +167 us (occupancy halved, spin thrash)
//   r23 chain-halving @ wave-cap  -> neutral (concurrency already capped)
//   r24 weight folding            -> neutral (dependent loads were free)
//   r25 L2-resident K-chunking    -> +14 us (latency not binding; instr 4x)
//   r26 LDS-atomic edge balancing -> +729 us (19M serialized ds_add_f32)
// Conclusion: tail is bound by per-CU scattered-miss concurrency at the
// 32-wave cap (time ~ 1/resident-blocks, insensitive to latency/ILP/
// balance); scatter bound by the 600K device-scope atomic RMW stream.
// This configuration is the empirical plateau.
// Structure: memset(cur) -> [gemm1 || CSR scatter] -> aggmm2 -> aggmm3
// -> agg_final. gemm+scatter: 512-thr blocks, waves 0-3 GEMM tile (W f32
// -> fp16 LDS transposed), waves 4-7 grid-stride scatter 4 edges/lane.
// aggmm: 512-thr blocks, 8 waves x 8 nodes (TPN=8 lanes/node, CPL chunks/
// lane, EU=4 with csr index prefetch) into As[64][K+8]; one barrier;
// waves 0-3 run 4 MFMA tiles. MFMA layouts guide-verified.
// ---------------------------------------------------------------------------

typedef _Float16 f16x8 __attribute__((ext_vector_type(8)));
typedef float f32x4 __attribute__((ext_vector_type(4)));

#define CSR_CAP 64

__device__ inline float2 h2f(unsigned int u) {
  __half2 h = __builtin_bit_cast(__half2, u);
  return __half22float2(h);
}

// acc0/acc1 += w * fp16x8(g)
__device__ inline void fma8h(float4& a0, float4& a1, const uint4& g, float w) {
  float2 f0 = h2f(g.x), f1 = h2f(g.y), f2 = h2f(g.z), f3 = h2f(g.w);
  a0.x = fmaf(f0.x, w, a0.x);
  a0.y = fmaf(f0.y, w, a0.y);
  a0.z = fmaf(f1.x, w, a0.z);
  a0.w = fmaf(f1.y, w, a0.w);
  a1.x = fmaf(f2.x, w, a1.x);
  a1.y = fmaf(f2.y, w, a1.y);
  a1.z = fmaf(f3.x, w, a1.z);
  a1.w = fmaf(f3.y, w, a1.w);
}

__device__ inline unsigned int pack2h(float x, float y) {
  __half2 h = __floats2half2_rn(x, y);
  return __builtin_bit_cast(unsigned int, h);
}

__device__ inline uint2 pack4h(const float4& v) {
  uint2 r;
  r.x = pack2h(v.x, v.y);
  r.y = pack2h(v.z, v.w);
  return r;
}

// -------------- GEMM (MFMA) with co-resident CSR scatter waves -------------
// Block = 512 threads. Threads [0,256): C16[n x F] = A[n x K] @ W[K x F];
//   W (f32) transposed+converted to fp16 LDS Ws[F][K+8]; 4 waves x 16 rows.
// Threads [256,512): grid-stride scatter, 4 edges/lane batches:
//   pos = atomic cursor on cur[d], store src id. cur[] ends the dispatch
//   equal to the in-degree histogram.
template <int K, int F, typename TIN>
__global__ __launch_bounds__(512) void gemm_mfma(const TIN* __restrict__ A,
                                                 const float* __restrict__ W,
                                                 __half* __restrict__ C16, int n,
                                                 int nwaves,
                                                 const int* __restrict__ src,
                                                 const int* __restrict__ dst,
                                                 int* __restrict__ cur,
                                                 int* __restrict__ csr, int E) {
  constexpr int KP = K + 8;
  constexpr int KS = K / 32;
  constexpr int NT = F / 16;

  __shared__ __half Ws[F * KP];

  int t = threadIdx.x;

  if (t >= 256) {
    // ---- scatter waves (4-7) ----
    __syncthreads();  // rendezvous with gemm waves' post-staging barrier
    int base = blockIdx.x * 256 + (t - 256);
    int stride = gridDim.x * 256;
    for (int e0 = base; e0 < E; e0 += 4 * stride) {
      int d[4], s[4];
      bool v[4];
#pragma unroll
      for (int u = 0; u < 4; ++u) {
        int e = e0 + u * stride;
        v[u] = e < E;
        int ee = v[u] ? e : 0;
        d[u] = dst[ee];
        s[u] = src[ee];
      }
      int pos[4];
#pragma unroll
      for (int u = 0; u < 4; ++u)
        if (v[u]) pos[u] = atomicAdd(&cur[d[u]], 1);
#pragma unroll
      for (int u = 0; u < 4; ++u)
        if (v[u]) {
          int p = pos[u] >= CSR_CAP ? CSR_CAP - 1 : pos[u];  // mem safety
          csr[(size_t)d[u] * CSR_CAP + p] = s[u];
        }
    }
    return;
  }

  // ---- gemm waves (0-3) ----
  for (int i = t; i < K * F; i += 256) {
    int kk = i / F, nn = i % F;
    Ws[nn * KP + kk] = __float2half(W[i]);
  }
  __syncthreads();  // only barrier

  int wave = blockIdx.x * 4 + (t >> 6);
  if (wave >= nwaves) return;
  int lane = t & 63;
  int m = lane & 15;
  int quad = lane >> 4;

  int arow = wave * 16 + m;
  if (arow >= n) arow = n - 1;  // clamp loads; stores guarded

  f16x8 af[KS];
  if constexpr (std::is_same_v<TIN, float>) {
#pragma unroll
    for (int ks = 0; ks < KS; ++ks) {
      const float* p = A + (size_t)arow * K + ks * 32 + quad * 8;
      float4 lo = *(const float4*)p;
      float4 hi = *(const float4*)(p + 4);
      f16x8 a;
      a[0] = (_Float16)lo.x; a[1] = (_Float16)lo.y;
      a[2] = (_Float16)lo.z; a[3] = (_Float16)lo.w;
      a[4] = (_Float16)hi.x; a[5] = (_Float16)hi.y;
      a[6] = (_Float16)hi.z; a[7] = (_Float16)hi.w;
      af[ks] = a;
    }
  } else {
#pragma unroll
    for (int ks = 0; ks < KS; ++ks)
      af[ks] = *(const f16x8*)(const void*)&A[(size_t)arow * K + ks * 32 + quad * 8];
  }

  f32x4 acc[NT];
#pragma unroll
  for (int nt = 0; nt < NT; ++nt) acc[nt] = (f32x4){0.f, 0.f, 0.f, 0.f};
#pragma unroll
  for (int nt = 0; nt < NT; ++nt)
#pragma unroll
    for (int ks = 0; ks < KS; ++ks) {
      f16x8 b = *(const f16x8*)(const void*)&Ws[(nt * 16 + m) * KP + ks * 32 + quad * 8];
      acc[nt] = __builtin_amdgcn_mfma_f32_16x16x32_f16(af[ks], b, acc[nt], 0, 0, 0);
    }

  int rbase = wave * 16 + quad * 4;
#pragma unroll
  for (int nt = 0; nt < NT; ++nt)
#pragma unroll
    for (int r = 0; r < 4; ++r) {
      int rr = rbase + r;
      if (rr < n) C16[(size_t)rr * F + nt * 16 + m] = __float2half(acc[nt][r]);
    }
}

// ---------------------- Fused aggregate + GEMM (MFMA) ----------------------
// C16[n x F] = relu(Agg(hprev) + bias) @ W,  hprev [n][K] fp16, W [K][F] f32.
// Block = 512 thr (8 waves) = 64 nodes = 4 MFMA tiles.
// Gather: all 8 waves, 8 nodes each (TPN=8 lanes/node, CPL chunks/lane),
// EU edge unroll, csr INDICES for the next batch prefetched before the FMA
// block of the current one. Edge weight rsqrt(cnt[s]+1)*di computed inline
// (cnt loads are L2-resident broadcasts).
// Results -> As[64][K+8] fp16. One barrier. MFMA: waves 0-3, tile each.
template <int K, int F, int CPL, int EU>
__global__ __launch_bounds__(512) void aggmm(
    const __half* __restrict__ hprev, const float* __restrict__ W,
    const float* __restrict__ bias, const int* __restrict__ cnt,
    const int* __restrict__ csr, __half* __restrict__ C16, int n) {
  constexpr int KP = K + 8;
  constexpr int KS = K / 32;
  constexpr int NT = F / 16;
  constexpr int TPN = 8;       // lanes per node
  constexpr int RS = K / 8;    // uint4 per row (TPN*CPL == RS)
  static_assert(TPN * CPL == RS, "chunk coverage");

  __shared__ __half Ws[F * KP];
  __shared__ __half As[64 * KP];

  int t = threadIdx.x;
  for (int i = t; i < K * F; i += 512) {
    int kk = i / F, nn = i % F;
    Ws[nn * KP + kk] = __float2half(W[i]);
  }

  int wid = t >> 6;
  int lane = t & 63;
  int nb = blockIdx.x * 64;

  // ---- gather phase (all 8 waves) ----
  {
    int sub = lane / TPN;     // node within wave (0..7)
    int fl = lane % TPN;      // chunk group
    int nib = wid * 8 + sub;  // node in block (0..63)
    int node = nb + nib;
    int nd = node < n ? node : n - 1;  // clamp (dup work OK; C-store guarded)
    const uint4* h4 = (const uint4*)hprev;
    int c0 = cnt[nd];
    float di = rsqrtf((float)c0 + 1.0f);
    float sc = di * di;
    int cc = c0 < CSR_CAP ? c0 : CSR_CAP;  // loop bound; mem safety
    float4 acc[CPL][2];
#pragma unroll
    for (int c = 0; c < CPL; ++c) {
      acc[c][0] = make_float4(0.f, 0.f, 0.f, 0.f);
      acc[c][1] = make_float4(0.f, 0.f, 0.f, 0.f);
    }
#pragma unroll
    for (int c = 0; c < CPL; ++c) {
      uint4 sv = h4[(size_t)nd * RS + fl + c * TPN];
      fma8h(acc[c][0], acc[c][1], sv, sc);
    }
    int j = nd * CSR_CAP;
    int e = j + cc;
    // initial preload: slots 0..EU-1 always in this node's region
    int p[EU];
#pragma unroll
    for (int u = 0; u < EU; ++u) p[u] = csr[j + u];
    for (; j + EU <= e;) {
      // gathers + degree loads for current batch (all p[] valid here)
      uint4 g[EU][CPL];
#pragma unroll
      for (int u = 0; u < EU; ++u)
#pragma unroll
        for (int c = 0; c < CPL; ++c) g[u][c] = h4[(size_t)p[u] * RS + fl + c * TPN];
      int cs[EU];
#pragma unroll
      for (int u = 0; u < EU; ++u) cs[u] = cnt[p[u]];
      j += EU;
      // prefetch next batch (reads <= EU-1 slots past region: padded alloc;
      // values only dereferenced if the loop continues -> valid edges)
      int pn[EU];
#pragma unroll
      for (int u = 0; u < EU; ++u) pn[u] = csr[j + u];
      // consume
#pragma unroll
      for (int u = 0; u < EU; ++u) {
        float w = rsqrtf((float)cs[u] + 1.0f) * di;
#pragma unroll
        for (int c = 0; c < CPL; ++c) fma8h(acc[c][0], acc[c][1], g[u][c], w);
      }
#pragma unroll
      for (int u = 0; u < EU; ++u) p[u] = pn[u];
    }
    // remainder (<EU edges): p[] holds csr[j..j+EU) already
#pragma unroll
    for (int u = 0; u < EU; ++u) {
      if (j + u < e) {
        float w = rsqrtf((float)cnt[p[u]] + 1.0f) * di;
#pragma unroll
        for (int c = 0; c < CPL; ++c) {
          uint4 g = h4[(size_t)p[u] * RS + fl + c * TPN];
          fma8h(acc[c][0], acc[c][1], g, w);
        }
      }
    }
#pragma unroll
    for (int c = 0; c < CPL; ++c) {
      int ch = fl + c * TPN;
      float4 b0 = *(const float4*)&bias[ch * 8];
      float4 b1 = *(const float4*)&bias[ch * 8 + 4];
      float4 r0 = make_float4(fmaxf(acc[c][0].x + b0.x, 0.f), fmaxf(acc[c][0].y + b0.y, 0.f),
                              fmaxf(acc[c][0].z + b0.z, 0.f), fmaxf(acc[c][0].w + b0.w, 0.f));
      float4 r1 = make_float4(fmaxf(acc[c][1].x + b1.x, 0.f), fmaxf(acc[c][1].y + b1.y, 0.f),
                              fmaxf(acc[c][1].z + b1.z, 0.f), fmaxf(acc[c][1].w + b1.w, 0.f));
      uint2 lo = pack4h(r0), hi = pack4h(r1);
      uint4 pk;
      pk.x = lo.x; pk.y = lo.y; pk.z = hi.x; pk.w = hi.y;
      *(uint4*)&As[(size_t)nib * KP + ch * 8] = pk;
    }
  }

  __syncthreads();

  // ---- MFMA phase (waves 0-3, one 16-row tile each) ----
  if (wid < 4) {
    int m = lane & 15;
    int quad = lane >> 4;
    const __half* At = &As[(size_t)wid * 16 * KP];
    f16x8 af[KS];
#pragma unroll
    for (int ks = 0; ks < KS; ++ks)
      af[ks] = *(const f16x8*)(const void*)&At[m * KP + ks * 32 + quad * 8];

    f32x4 acc2[NT];
#pragma unroll
    for (int nt = 0; nt < NT; ++nt) acc2[nt] = (f32x4){0.f, 0.f, 0.f, 0.f};
#pragma unroll
    for (int nt = 0; nt < NT; ++nt)
#pragma unroll
      for (int ks = 0; ks < KS; ++ks) {
        f16x8 bfr = *(const f16x8*)(const void*)&Ws[(nt * 16 + m) * KP + ks * 32 + quad * 8];
        acc2[nt] = __builtin_amdgcn_mfma_f32_16x16x32_f16(af[ks], bfr, acc2[nt], 0, 0, 0);
      }

    int rbase = nb + wid * 16 + quad * 4;
#pragma unroll
    for (int nt = 0; nt < NT; ++nt)
#pragma unroll
      for (int r = 0; r < 4; ++r) {
        int rr = rbase + r;
        if (rr < n) C16[(size_t)rr * F + nt * 16 + m] = __float2half(acc2[nt][r]);
      }
  }
}

// ------------------------------ Final aggregation --------------------------
// out[i] = Agg(h16)[i] + bias (f32 out, F=16). 4 lanes/node: 2 edge-halves x
// 2 chunk-lanes; halves combined via shfl_xor(2). 64 nodes/block.
__global__ __launch_bounds__(256) void agg_final(
    const __half* __restrict__ h16, const int* __restrict__ cnt,
    const int* __restrict__ csr, const float* __restrict__ bias,
    float* __restrict__ out, int n) {
  int node = blockIdx.x * 64 + threadIdx.x / 4;
  int q = threadIdx.x & 3;
  int half = q >> 1;
  int fl = q & 1;
  bool valid = node < n;
  int nd = valid ? node : n - 1;

  const uint4* h4 = (const uint4*)h16;  // 2 uint4 per row
  int c0 = cnt[nd];
  float di = rsqrtf((float)c0 + 1.0f);
  int cc = c0 < CSR_CAP ? c0 : CSR_CAP;
  float4 a0 = make_float4(0.f, 0.f, 0.f, 0.f);
  float4 a1 = make_float4(0.f, 0.f, 0.f, 0.f);
  if (half == 0) {
    uint4 sv = h4[(size_t)nd * 2 + fl];
    fma8h(a0, a1, sv, di * di);
  }
  int s = nd * CSR_CAP;
  int e = s + cc;
  int j = s + half;
  for (; j + 2 < e; j += 4) {  // edges j, j+2 (this half's stride-2 stream)
    int p0 = csr[j];
    int p1 = csr[j + 2];
    int ca = cnt[p0];
    int cb = cnt[p1];
    uint4 g0 = h4[(size_t)p0 * 2 + fl];
    uint4 g1 = h4[(size_t)p1 * 2 + fl];
    fma8h(a0, a1, g0, rsqrtf((float)ca + 1.0f) * di);
    fma8h(a0, a1, g1, rsqrtf((float)cb + 1.0f) * di);
  }
  for (; j < e; j += 2) {
    int p = csr[j];
    uint4 g = h4[(size_t)p * 2 + fl];
    fma8h(a0, a1, g, rsqrtf((float)cnt[p] + 1.0f) * di);
  }

  // combine the two edge-halves (xor lane by 2 keeps fl, flips half)
  a0.x += __shfl_xor(a0.x, 2);
  a0.y += __shfl_xor(a0.y, 2);
  a0.z += __shfl_xor(a0.z, 2);
  a0.w += __shfl_xor(a0.w, 2);
  a1.x += __shfl_xor(a1.x, 2);
  a1.y += __shfl_xor(a1.y, 2);
  a1.z += __shfl_xor(a1.z, 2);
  a1.w += __shfl_xor(a1.w, 2);

  if (valid && half == 0) {
    float4 b0 = *(const float4*)&bias[fl * 8];
    float4 b1 = *(const float4*)&bias[fl * 8 + 4];
    float4 r0 = make_float4(a0.x + b0.x, a0.y + b0.y, a0.z + b0.z, a0.w + b0.w);
    float4 r1 = make_float4(a1.x + b1.x, a1.y + b1.y, a1.z + b1.z, a1.w + b1.w);
    float* op = &out[(size_t)node * 16 + fl * 8];
    *(float4*)op = r0;
    *(float4*)(op + 4) = r1;
  }
}

// -------------------------------- launch -----------------------------------

extern "C" void kernel_launch(void* const* d_in, const int* in_sizes, int n_in,
                              void* d_out, int out_size, void* d_ws, size_t ws_size,
                              hipStream_t stream) {
  const float* x = (const float*)d_in[0];
  const int* edge = (const int*)d_in[1];
  const float* W1 = (const float*)d_in[2];
  const float* b1 = (const float*)d_in[3];
  const float* W2 = (const float*)d_in[4];
  const float* b2 = (const float*)d_in[5];
  const float* W3 = (const float*)d_in[6];
  const float* b3 = (const float*)d_in[7];

  const int N = in_sizes[0] / 128;
  const int E = in_sizes[1] / 2;
  const int* src = edge;       // edge_index[0]
  const int* dstp = edge + E;  // edge_index[1]
  float* out = (float*)d_out;

  size_t off = 0;
  auto take = [&](size_t bytes) -> void* {
    void* r = (char*)d_ws + off;
    off += (bytes + 255) & ~(size_t)255;
    return r;
  };
  int* cur = (int*)take((size_t)N * 4);                   // cursors -> in-degrees
  int* csr = (int*)take((size_t)N * CSR_CAP * 4 + 256);   // src-only CSR + prefetch pad
  __half* t1 = (__half*)take((size_t)N * 128 * 2);        // gemm1 out
  __half* t2 = (__half*)take((size_t)N * 64 * 2);         // aggmm2 out
  __half* t3 = (__half*)take((size_t)N * 16 * 2);         // aggmm3 out

  // zero cur (first region only)
  hipMemsetAsync(d_ws, 0, ((size_t)N * 4 + 255) & ~(size_t)255, stream);

  int nwaves = (N + 15) / 16;   // 3125
  int gblk = (nwaves + 3) / 4;  // 782
  int fblk = (N + 63) / 64;     // 782

  // gemm1 with co-resident CSR scatter (waves 4-7 of every block grid-stride
  // the edge list; cur[] ends this dispatch holding the in-degree histogram).
  gemm_mfma<128, 128, float><<<gblk, 512, 0, stream>>>(x, W1, t1, N, nwaves,
                                                       src, dstp, cur, csr, E);

  // t2 = relu(Agg(t1)+b1) @ W2    (K=128: CPL=2, EU=4 -> 8 gathers in flight)
  aggmm<128, 64, 2, 4><<<fblk, 512, 0, stream>>>(t1, W2, b1, cur, csr, t2, N);
  // t3 = relu(Agg(t2)+b2) @ W3    (K=64: CPL=1, EU=4)
  aggmm<64, 16, 1, 4><<<fblk, 512, 0, stream>>>(t2, W3, b2, cur, csr, t3, N);
  // out = Agg(t3) + b3
  agg_final<<<fblk, 256, 0, stream>>>(t3, cur, csr, b3, out, N);
}